// Round 8
// baseline (595.262 us; speedup 1.0000x reference)
//
#include <hip/hip_runtime.h>
#include <math.h>

// Shapes
constexpr int BATCH = 16;
constexpr int CH    = 512;
constexpr int NPIX  = 625;   // 25*25 == 5*125
constexpr int HEADS = 8;
constexpr int HDIM  = 64;
constexpr int HIDD  = 2048;

constexpr float EPS_LN = 1e-5f;
constexpr float EPS_BN = 1e-5f;
constexpr float SCALE  = 0.125f;   // hd^-0.5, both attentions

typedef __bf16 bf16x8 __attribute__((ext_vector_type(8)));
typedef float  f32x4  __attribute__((ext_vector_type(4)));
typedef unsigned u32x4 __attribute__((ext_vector_type(4)));

static __device__ inline unsigned pack_bf16(float lo, float hi) {
  union { __bf16 h; unsigned short u; } a, b;
  a.h = (__bf16)lo; b.h = (__bf16)hi;
  return ((unsigned)b.u << 16) | (unsigned)a.u;
}

// ---------------------------------------------------------------------------
// Channel LayerNorm v2 (unchanged).
// ---------------------------------------------------------------------------
__global__ __launch_bounds__(256) void ln_kernel2(
    const float* __restrict__ x, const float* __restrict__ g,
    const float* __restrict__ bt, float* __restrict__ y) {
  __shared__ float ps[4][64];
  __shared__ float pss[4][64];
  int lane = threadIdx.x & 63;
  int w    = threadIdx.x >> 6;
  int b    = blockIdx.y;
  int i    = blockIdx.x * 64 + lane;
  int ic   = i < NPIX ? i : NPIX - 1;
  const float* xb = x + (size_t)b * CH * NPIX + ic;
  float s = 0.f, ss = 0.f;
  #pragma unroll 4
  for (int c = w * 128; c < w * 128 + 128; ++c) {
    float v = xb[(size_t)c * NPIX];
    s += v; ss += v * v;
  }
  ps[w][lane] = s; pss[w][lane] = ss;
  __syncthreads();
  float st  = ps[0][lane] + ps[1][lane] + ps[2][lane] + ps[3][lane];
  float sst = pss[0][lane] + pss[1][lane] + pss[2][lane] + pss[3][lane];
  float mean = st * (1.0f / CH);
  float var  = sst * (1.0f / CH) - mean * mean;
  float inv  = 1.0f / (sqrtf(fmaxf(var, 0.0f)) + EPS_LN);
  if (i >= NPIX) return;
  float* yb = y + (size_t)b * CH * NPIX + i;
  #pragma unroll 4
  for (int c = w * 128; c < w * 128 + 128; ++c) {
    float v = xb[(size_t)c * NPIX];
    yb[(size_t)c * NPIX] = (v - mean) * inv * g[c] + bt[c];
  }
}

// ---------------------------------------------------------------------------
// First depthwise conv (25x25): three convs in one pass, f32 out. (unchanged)
// ---------------------------------------------------------------------------
__global__ void dwconv3_kernel(const float* __restrict__ src,
    const float* __restrict__ w0, const float* __restrict__ b0,
    const float* __restrict__ w1, const float* __restrict__ b1,
    const float* __restrict__ w2, const float* __restrict__ b2,
    float* __restrict__ d0, float* __restrict__ d1, float* __restrict__ d2,
    int Hc, int Wc) {
  size_t idx = (size_t)blockIdx.x * blockDim.x + threadIdx.x;
  size_t total = (size_t)BATCH * CH * Hc * Wc;
  if (idx >= total) return;
  int wp = (int)(idx % Wc);
  int hp = (int)((idx / Wc) % Hc);
  int c  = (int)((idx / ((size_t)Wc * Hc)) % CH);
  const float* f0 = w0 + c * 9;
  const float* f1 = w1 + c * 9;
  const float* f2 = w2 + c * 9;
  float a0 = 0.f, a1 = 0.f, a2 = 0.f;
  #pragma unroll
  for (int kh = -1; kh <= 1; ++kh) {
    int h2 = hp + kh; if (h2 < 0 || h2 >= Hc) continue;
    #pragma unroll
    for (int kw = -1; kw <= 1; ++kw) {
      int w2p = wp + kw; if (w2p < 0 || w2p >= Wc) continue;
      float v = src[idx + (size_t)kh * Wc + kw];
      int wi = (kh + 1) * 3 + (kw + 1);
      a0 += v * f0[wi]; a1 += v * f1[wi]; a2 += v * f2[wi];
    }
  }
  d0[idx] = a0 + b0[c];
  d1[idx] = a1 + b1[c];
  d2[idx] = a2 + b2[c];
}

// ---------------------------------------------------------------------------
// spe depthwise conv (5x125): q,k -> bf16 [c][640] padded; v -> f32. (unchanged)
// ---------------------------------------------------------------------------
__global__ void dwconv_spe_kernel(const float* __restrict__ src,
    const float* __restrict__ w0, const float* __restrict__ b0,
    const float* __restrict__ w1, const float* __restrict__ b1,
    const float* __restrict__ w2, const float* __restrict__ b2,
    __bf16* __restrict__ q16, __bf16* __restrict__ k16, float* __restrict__ v) {
  size_t idx = (size_t)blockIdx.x * blockDim.x + threadIdx.x;
  if (idx >= (size_t)BATCH * CH * 640) return;
  int n = (int)(idx % 640);
  int c = (int)((idx / 640) % CH);
  int b = (int)(idx / ((size_t)640 * CH));
  if (n >= NPIX) { q16[idx] = (__bf16)0.f; k16[idx] = (__bf16)0.f; return; }
  int hp = n / 125, wp = n % 125;
  size_t base = ((size_t)b * CH + c) * NPIX;
  const float* f0 = w0 + c * 9;
  const float* f1 = w1 + c * 9;
  const float* f2 = w2 + c * 9;
  float a0 = 0.f, a1 = 0.f, a2 = 0.f;
  #pragma unroll
  for (int kh = -1; kh <= 1; ++kh) {
    int h2 = hp + kh; if (h2 < 0 || h2 >= 5) continue;
    #pragma unroll
    for (int kw = -1; kw <= 1; ++kw) {
      int w2p = wp + kw; if (w2p < 0 || w2p >= 125) continue;
      float vv = src[base + h2 * 125 + w2p];
      int wi = (kh + 1) * 3 + (kw + 1);
      a0 += vv * f0[wi]; a1 += vv * f1[wi]; a2 += vv * f2[wi];
    }
  }
  q16[idx] = (__bf16)(a0 + b0[c]);
  k16[idx] = (__bf16)(a1 + b1[c]);
  v[base + n] = a2 + b2[c];
}

// ---------------------------------------------------------------------------
// Transpose+cast q,k: [b][h*64+d][n] f32 -> [bh][n][64] bf16. (unchanged)
// ---------------------------------------------------------------------------
__global__ __launch_bounds__(256) void qk_to_bf16T(
    const float* __restrict__ q, const float* __restrict__ k,
    __bf16* __restrict__ qT, __bf16* __restrict__ kT) {
  __shared__ __bf16 tq[64][65];
  __shared__ __bf16 tk[64][65];
  int bh = blockIdx.y;
  int n0 = blockIdx.x * 64;
  int b = bh >> 3, h = bh & 7;
  const float* qb = q + (size_t)(b * CH + h * HDIM) * NPIX;
  const float* kb = k + (size_t)(b * CH + h * HDIM) * NPIX;
  #pragma unroll
  for (int it = 0; it < 16; ++it) {
    int idx = threadIdx.x + it * 256;
    int d = idx >> 6, n = idx & 63;
    int nn = n0 + n;
    float qv = (nn < NPIX) ? qb[(size_t)d * NPIX + nn] : 0.f;
    float kv = (nn < NPIX) ? kb[(size_t)d * NPIX + nn] : 0.f;
    tq[n][d] = (__bf16)qv;
    tk[n][d] = (__bf16)kv;
  }
  __syncthreads();
  size_t obase = (size_t)bh * NPIX;
  #pragma unroll
  for (int it = 0; it < 16; ++it) {
    int idx = threadIdx.x + it * 256;
    int n = idx >> 6, d = idx & 63;
    int nn = n0 + n;
    if (nn < NPIX) {
      qT[(obase + nn) * 64 + d] = tq[n][d];
      kT[(obase + nn) * 64 + d] = tk[n][d];
    }
  }
}

// v: [c][625] f32 -> [c][640] bf16. (unchanged)
__global__ void v_to_bf16(const float* __restrict__ v, __bf16* __restrict__ v16) {
  int row = blockIdx.x;
  const float* src = v + (size_t)row * NPIX;
  __bf16* dst = v16 + (size_t)row * 640;
  for (int n = threadIdx.x; n < NPIX; n += 256) dst[n] = (__bf16)src[n];
}

// ---------------------------------------------------------------------------
// MFMA head attention v5: 64 q-rows/block, swapped QK^T, register-resident P.
// Wave w owns q-rows [i0+16w, i0+16w+16). Phase 1: S^T = mfma(K,Q) so each
// LANE holds a full key-slice for ONE q-row -> softmax is lane-local + 2
// shfl_xor; no max-subtraction (|S|<0.05, exp exact in f32); P kept as packed
// bf16 in 80 VGPRs. Phase 2: PV with A-frags assembled by 8 shfl + selects
// (no LDS). Only LDS: output transpose staging. K/V L2 traffic /4 vs v4.
// ---------------------------------------------------------------------------
__global__ __launch_bounds__(256) void head_attn_mfma5(
    const __bf16* __restrict__ qT, const __bf16* __restrict__ kT,
    const __bf16* __restrict__ vB, float* __restrict__ out) {
  __shared__ float lds_o[64][68];
  int t = threadIdx.x;
  int w = t >> 6, lane = t & 63, g = lane >> 4, li = lane & 15;
  int h = blockIdx.y, b = blockIdx.z;
  int bh = b * HEADS + h;
  int i0 = blockIdx.x * 64;
  int qr0 = i0 + w * 16;
  const __bf16* Qb = qT + (size_t)bh * NPIX * 64;
  const __bf16* Kb = kT + (size_t)bh * NPIX * 64;

  // B-frag: Q rows (lane li -> q-row qr0+li)
  bf16x8 bq0, bq1;
  {
    int qr = qr0 + li; if (qr > NPIX - 1) qr = NPIX - 1;
    const __bf16* qp = Qb + (size_t)qr * 64 + 8 * g;
    bq0 = *(const bf16x8*)(qp);
    bq1 = *(const bf16x8*)(qp + 32);
  }

  // ---- phase 1: S^T frags; lane (g,li) holds S[key=cf*16+4g+r][q=li] ----
  uint2 pv[40];
  float suml = 0.f;
  #pragma unroll
  for (int cf = 0; cf < 40; ++cf) {
    int kr = cf * 16 + li; if (kr > NPIX - 1) kr = NPIX - 1;
    const __bf16* kp = Kb + (size_t)kr * 64 + 8 * g;
    bf16x8 ak0 = *(const bf16x8*)(kp);
    bf16x8 ak1 = *(const bf16x8*)(kp + 32);
    f32x4 a = (f32x4){0.f, 0.f, 0.f, 0.f};
    a = __builtin_amdgcn_mfma_f32_16x16x32_bf16(ak0, bq0, a, 0, 0, 0);
    a = __builtin_amdgcn_mfma_f32_16x16x32_bf16(ak1, bq1, a, 0, 0, 0);
    float e0 = __expf(a[0] * SCALE);
    float e1 = __expf(a[1] * SCALE);
    float e2 = __expf(a[2] * SCALE);
    float e3 = __expf(a[3] * SCALE);
    if (cf == 39) {   // keys 624+4g+r: only (g==0, r==0) valid
      e1 = 0.f; e2 = 0.f; e3 = 0.f;
      if (g > 0) e0 = 0.f;
    }
    suml += e0 + e1 + e2 + e3;
    pv[cf].x = pack_bf16(e0, e1);
    pv[cf].y = pack_bf16(e2, e3);
  }
  // combine over the 4 g-lanes sharing the same li (q-row)
  suml += __shfl_xor(suml, 16);
  suml += __shfl_xor(suml, 32);
  float inv = 1.0f / suml;
  // redistribute: lane needs inv of q-row 4g+r (held by lane index 4g+r)
  float invr[4];
  #pragma unroll
  for (int r = 0; r < 4; ++r) invr[r] = __shfl(inv, 4 * g + r);

  // ---- phase 2: O = P @ V, A-frags built in-register via shfl ----
  const __bf16* Vb = vB + (size_t)(b * CH + h * HDIM) * 640;
  f32x4 o[4];
  #pragma unroll
  for (int dg = 0; dg < 4; ++dg) o[dg] = (f32x4){0.f, 0.f, 0.f, 0.f};
  int L0 = ((2 * g) & 3) * 16 + li;
  int L1 = L0 + 16;
  bool hi = (g >= 2);
  #pragma unroll
  for (int ks = 0; ks < 20; ++ks) {
    int xA0 = (int)pv[2 * ks].x,     xA1 = (int)pv[2 * ks].y;
    int xB0 = (int)pv[2 * ks + 1].x, xB1 = (int)pv[2 * ks + 1].y;
    int a0A = __shfl(xA0, L0), a0B = __shfl(xB0, L0);
    int a1A = __shfl(xA1, L0), a1B = __shfl(xB1, L0);
    int a2A = __shfl(xA0, L1), a2B = __shfl(xB0, L1);
    int a3A = __shfl(xA1, L1), a3B = __shfl(xB1, L1);
    u32x4 aw;
    aw[0] = (unsigned)(hi ? a0B : a0A);
    aw[1] = (unsigned)(hi ? a1B : a1A);
    aw[2] = (unsigned)(hi ? a2B : a2A);
    aw[3] = (unsigned)(hi ? a3B : a3A);
    bf16x8 pa = __builtin_bit_cast(bf16x8, aw);
    #pragma unroll
    for (int dg = 0; dg < 4; ++dg) {
      bf16x8 bv = *(const bf16x8*)(Vb + (size_t)(dg * 16 + li) * 640 + ks * 32 + 8 * g);
      o[dg] = __builtin_amdgcn_mfma_f32_16x16x32_bf16(pa, bv, o[dg], 0, 0, 0);
    }
  }

  // ---- epilogue: normalize + transpose via LDS, coalesced store ----
  #pragma unroll
  for (int dg = 0; dg < 4; ++dg) {
    #pragma unroll
    for (int r = 0; r < 4; ++r)
      lds_o[w * 16 + 4 * g + r][dg * 16 + li] = o[dg][r] * invr[r];
  }
  __syncthreads();
  size_t cbase = (size_t)(b * CH + h * HDIM);
  int qmax = NPIX - i0;          // 64, or 49 for the last tile
  #pragma unroll
  for (int it = 0; it < 16; ++it) {
    int e = t + it * 256;
    int q = e & 63, d = e >> 6;
    if (q < qmax) out[(cbase + d) * NPIX + i0 + q] = lds_o[q][d];
  }
}

// ---------------------------------------------------------------------------
// MFMA channel attention v2 (unchanged from round 6).
// ---------------------------------------------------------------------------
__global__ __launch_bounds__(256) void chan_attn_mfma2(
    const __bf16* __restrict__ sq, const __bf16* __restrict__ sk,
    __bf16* __restrict__ Am) {
  __shared__ float red_max[4][16];
  __shared__ float red_sum[4][16];
  int t = threadIdx.x;
  int w = t >> 6, lane = t & 63, g = lane >> 4, li = lane & 15;
  int b = blockIdx.y;
  int cq0 = blockIdx.x * 16;
  const __bf16* qrow  = sq + ((size_t)b * CH + cq0 + li) * 640 + 8 * g;
  const __bf16* kbase = sk + ((size_t)b * CH + w * 128 + li) * 640 + 8 * g;
  f32x4 acc[8];
  #pragma unroll
  for (int i = 0; i < 8; ++i) acc[i] = (f32x4){0.f, 0.f, 0.f, 0.f};
  for (int ks = 0; ks < 20; ++ks) {
    bf16x8 af = *(const bf16x8*)(qrow + ks * 32);
    #pragma unroll
    for (int cfl = 0; cfl < 8; ++cfl) {
      bf16x8 bfr = *(const bf16x8*)(kbase + (size_t)cfl * 16 * 640 + ks * 32);
      acc[cfl] = __builtin_amdgcn_mfma_f32_16x16x32_bf16(af, bfr, acc[cfl], 0, 0, 0);
    }
  }
  #pragma unroll
  for (int i = 0; i < 8; ++i) acc[i] = acc[i] * SCALE;

  #pragma unroll
  for (int r = 0; r < 4; ++r) {
    float mx = acc[0][r];
    #pragma unroll
    for (int cfl = 1; cfl < 8; ++cfl) mx = fmaxf(mx, acc[cfl][r]);
    mx = fmaxf(mx, __shfl_xor(mx, 1));
    mx = fmaxf(mx, __shfl_xor(mx, 2));
    mx = fmaxf(mx, __shfl_xor(mx, 4));
    mx = fmaxf(mx, __shfl_xor(mx, 8));
    if (li == 0) red_max[w][4 * g + r] = mx;
  }
  __syncthreads();

  #pragma unroll
  for (int r = 0; r < 4; ++r) {
    int row = 4 * g + r;
    float mx = fmaxf(fmaxf(red_max[0][row], red_max[1][row]),
                     fmaxf(red_max[2][row], red_max[3][row]));
    float sum = 0.f;
    #pragma unroll
    for (int cfl = 0; cfl < 8; ++cfl) {
      float p = __expf(acc[cfl][r] - mx);
      acc[cfl][r] = p;
      sum += p;
    }
    sum += __shfl_xor(sum, 1);
    sum += __shfl_xor(sum, 2);
    sum += __shfl_xor(sum, 4);
    sum += __shfl_xor(sum, 8);
    if (li == 0) red_sum[w][row] = sum;
  }
  __syncthreads();

  __bf16* Ab = Am + ((size_t)b * CH + cq0) * CH + w * 128;
  #pragma unroll
  for (int r = 0; r < 4; ++r) {
    int row = 4 * g + r;
    float l = red_sum[0][row] + red_sum[1][row] + red_sum[2][row] + red_sum[3][row];
    float inv = 1.0f / l;
    #pragma unroll
    for (int cfl = 0; cfl < 8; ++cfl)
      Ab[(size_t)row * CH + cfl * 16 + li] = (__bf16)(acc[cfl][r] * inv);
  }
}

// ---------------------------------------------------------------------------
// NT bf16 MFMA GEMM (unchanged, verified round 2).
// ---------------------------------------------------------------------------
template <int EPI>
__global__ __launch_bounds__(256) void gemm_nt(
    const __bf16* __restrict__ A, long long aBatch,
    const __bf16* __restrict__ B, long long bBatch,
    void* __restrict__ Cout, long long cBatch,
    int M, int N, int K,
    const float* __restrict__ p0, const float* __restrict__ p1,
    const float* __restrict__ res, long long resBatch) {
  __shared__ __align__(16) union {
    struct { unsigned char As[128 * 128]; unsigned char Bs[64 * 128]; } s;
    float Ce[4][64][17];
  } u;
  int t = threadIdx.x;
  int w = t >> 6, lane = t & 63, g = lane >> 4, li = lane & 15;
  int wm = w & 1, wn = w >> 1;
  int n0 = blockIdx.x * 64, m0 = blockIdx.y * 128, b = blockIdx.z;
  const __bf16* Ab = A + (size_t)b * aBatch;
  const __bf16* Bb = B + (size_t)b * bBatch;
  f32x4 acc[4][2];
  #pragma unroll
  for (int i = 0; i < 4; ++i)
    #pragma unroll
    for (int j = 0; j < 2; ++j) acc[i][j] = (f32x4){0.f, 0.f, 0.f, 0.f};

  for (int k0 = 0; k0 < K; k0 += 64) {
    bf16x8 ra[4], rb[2];
    #pragma unroll
    for (int i = 0; i < 4; ++i) {
      int e = t + i * 256;
      int row = e >> 3, cc = e & 7;
      int ar = m0 + row; ar = ar < M ? ar : M - 1;
      ra[i] = *(const bf16x8*)(Ab + (size_t)ar * K + k0 + cc * 8);
    }
    #pragma unroll
    for (int i = 0; i < 2; ++i) {
      int e = t + i * 256;
      int row = e >> 3, cc = e & 7;
      rb[i] = *(const bf16x8*)(Bb + (size_t)(n0 + row) * K + k0 + cc * 8);
    }
    __syncthreads();
    #pragma unroll
    for (int i = 0; i < 4; ++i) {
      int e = t + i * 256; int row = e >> 3, cc = e & 7;
      int off = (row * 128 + cc * 16) ^ ((row & 7) << 4);
      *(bf16x8*)(&u.s.As[off]) = ra[i];
    }
    #pragma unroll
    for (int i = 0; i < 2; ++i) {
      int e = t + i * 256; int row = e >> 3, cc = e & 7;
      int off = (row * 128 + cc * 16) ^ ((row & 7) << 4);
      *(bf16x8*)(&u.s.Bs[off]) = rb[i];
    }
    __syncthreads();
    #pragma unroll
    for (int ks = 0; ks < 2; ++ks) {
      bf16x8 af[4], bfr[2];
      #pragma unroll
      for (int mf = 0; mf < 4; ++mf) {
        int row = wm * 64 + mf * 16 + li;
        int off = (row * 128 + ks * 64 + g * 16) ^ ((row & 7) << 4);
        af[mf] = *(const bf16x8*)(&u.s.As[off]);
      }
      #pragma unroll
      for (int nf = 0; nf < 2; ++nf) {
        int row = wn * 32 + nf * 16 + li;
        int off = (row * 128 + ks * 64 + g * 16) ^ ((row & 7) << 4);
        bfr[nf] = *(const bf16x8*)(&u.s.Bs[off]);
      }
      #pragma unroll
      for (int mf = 0; mf < 4; ++mf)
        #pragma unroll
        for (int nf = 0; nf < 2; ++nf)
          acc[mf][nf] = __builtin_amdgcn_mfma_f32_16x16x32_bf16(
              af[mf], bfr[nf], acc[mf][nf], 0, 0, 0);
    }
    __syncthreads();
  }

  #pragma unroll
  for (int p = 0; p < 2; ++p) {
    __syncthreads();
    #pragma unroll
    for (int mf = 0; mf < 4; ++mf) {
      #pragma unroll
      for (int r = 0; r < 4; ++r)
        u.Ce[w][mf * 16 + 4 * g + r][li] = acc[mf][p][r];
    }
    __syncthreads();
    int m = m0 + wm * 64 + lane;
    int colb = n0 + wn * 32 + p * 16;
    if (m < M) {
      float vv[16];
      #pragma unroll
      for (int c = 0; c < 16; ++c) vv[c] = u.Ce[w][lane][c];
      if (EPI == 0) {
        __bf16* Cb = (__bf16*)Cout + (size_t)b * cBatch + (size_t)m * N + colb;
        bf16x8 o0, o1;
        #pragma unroll
        for (int j = 0; j < 8; ++j) { o0[j] = (__bf16)vv[j]; o1[j] = (__bf16)vv[8 + j]; }
        *(bf16x8*)(Cb) = o0;
        *(bf16x8*)(Cb + 8) = o1;
      } else if (EPI == 1) {
        float* Cf = (float*)Cout + (size_t)b * cBatch + (size_t)m * N + colb;
        const float* rp = res + (size_t)b * resBatch + (size_t)m * N + colb;
        #pragma unroll
        for (int c = 0; c < 16; ++c)
          vv[c] = vv[c] * p0[colb + c] + p1[colb + c] + rp[c];
        #pragma unroll
        for (int c4 = 0; c4 < 4; ++c4)
          *(f32x4*)(Cf + c4 * 4) = (f32x4){vv[c4*4], vv[c4*4+1], vv[c4*4+2], vv[c4*4+3]};
      } else if (EPI == 2) {
        __bf16* Cb = (__bf16*)Cout + (size_t)b * cBatch + (size_t)m * N + colb;
        #pragma unroll
        for (int c = 0; c < 16; ++c) {
          float xg = vv[c] + p0[colb + c];
          vv[c] = 0.5f * xg * (1.0f + erff(xg * 0.70710678118654752f));
        }
        bf16x8 o0, o1;
        #pragma unroll
        for (int j = 0; j < 8; ++j) { o0[j] = (__bf16)vv[j]; o1[j] = (__bf16)vv[8 + j]; }
        *(bf16x8*)(Cb) = o0;
        *(bf16x8*)(Cb + 8) = o1;
      } else {
        float* Cf = (float*)Cout + (size_t)b * cBatch + (size_t)m * N + colb;
        const float* rp = res + (size_t)b * resBatch + (size_t)m * N + colb;
        #pragma unroll
        for (int c = 0; c < 16; ++c)
          vv[c] = vv[c] + p0[colb + c] + rp[c];
        #pragma unroll
        for (int c4 = 0; c4 < 4; ++c4)
          *(f32x4*)(Cf + c4 * 4) = (f32x4){vv[c4*4], vv[c4*4+1], vv[c4*4+2], vv[c4*4+3]};
      }
    }
  }
}

// ---------------------------------------------------------------------------
// Batched tiled transpose (unchanged).
// ---------------------------------------------------------------------------
template <typename TO>
__global__ __launch_bounds__(256) void transpose_bat(
    const float* __restrict__ in, TO* __restrict__ out, int R, int Cc) {
  __shared__ float tile[64][65];
  int b = blockIdx.z;
  int c0 = blockIdx.x * 64, r0 = blockIdx.y * 64;
  const float* ib = in + (size_t)b * R * Cc;
  TO* ob = out + (size_t)b * R * Cc;
  for (int e = threadIdx.x; e < 4096; e += 256) {
    int rr = e >> 6, cc = e & 63;
    int r = r0 + rr, c = c0 + cc;
    tile[rr][cc] = (r < R && c < Cc) ? ib[(size_t)r * Cc + c] : 0.f;
  }
  __syncthreads();
  for (int e = threadIdx.x; e < 4096; e += 256) {
    int cc = e >> 6, rr = e & 63;
    int r = r0 + rr, c = c0 + cc;
    if (r < R && c < Cc) ob[(size_t)c * R + r] = (TO)tile[rr][cc];
  }
}

// ---------------------------------------------------------------------------
// Row LayerNorm (unchanged).
// ---------------------------------------------------------------------------
__global__ __launch_bounds__(256) void ln2_row_kernel(
    const float* __restrict__ y, const float* __restrict__ g,
    const float* __restrict__ bt, __bf16* __restrict__ o) {
  int row = blockIdx.x * 4 + (threadIdx.x >> 6);
  int lane = threadIdx.x & 63;
  const float* yr = y + (size_t)row * CH + lane * 8;
  f32x4 v0 = *(const f32x4*)(yr);
  f32x4 v1 = *(const f32x4*)(yr + 4);
  float s = v0[0]+v0[1]+v0[2]+v0[3]+v1[0]+v1[1]+v1[2]+v1[3];
  float ss = v0[0]*v0[0]+v0[1]*v0[1]+v0[2]*v0[2]+v0[3]*v0[3]
           + v1[0]*v1[0]+v1[1]*v1[1]+v1[2]*v1[2]+v1[3]*v1[3];
  #pragma unroll
  for (int off = 32; off > 0; off >>= 1) {
    s  += __shfl_xor(s, off);
    ss += __shfl_xor(ss, off);
  }
  float mean = s * (1.0f / CH);
  float var  = ss * (1.0f / CH) - mean * mean;
  float inv  = 1.0f / (sqrtf(fmaxf(var, 0.0f)) + EPS_LN);
  f32x4 g0 = *(const f32x4*)(g + lane * 8);
  f32x4 g1 = *(const f32x4*)(g + lane * 8 + 4);
  f32x4 b0 = *(const f32x4*)(bt + lane * 8);
  f32x4 b1 = *(const f32x4*)(bt + lane * 8 + 4);
  bf16x8 ov;
  #pragma unroll
  for (int j = 0; j < 4; ++j) ov[j]     = (__bf16)((v0[j] - mean) * inv * g0[j] + b0[j]);
  #pragma unroll
  for (int j = 0; j < 4; ++j) ov[4 + j] = (__bf16)((v1[j] - mean) * inv * g1[j] + b1[j]);
  *(bf16x8*)(o + (size_t)row * CH + lane * 8) = ov;
}

__global__ void cast_bf16_kernel(const float* __restrict__ s, __bf16* __restrict__ d, int n) {
  int i = blockIdx.x * 256 + threadIdx.x;
  if (i < n) d[i] = (__bf16)s[i];
}

__global__ void bn_prep(const float* __restrict__ g, const float* __restrict__ bt,
                        const float* __restrict__ mean, const float* __restrict__ var,
                        float* __restrict__ scale, float* __restrict__ shift) {
  int c = blockIdx.x * blockDim.x + threadIdx.x;
  if (c >= CH) return;
  float s = g[c] * rsqrtf(var[c] + EPS_BN);
  scale[c] = s;
  shift[c] = bt[c] - mean[c] * s;
}

// ---------------------------------------------------------------------------
extern "C" void kernel_launch(void* const* d_in, const int* in_sizes, int n_in,
                              void* d_out, int out_size, void* d_ws, size_t ws_size,
                              hipStream_t stream) {
  const float* x      = (const float*)d_in[0];
  const float* ln1_g  = (const float*)d_in[1];
  const float* ln1_b  = (const float*)d_in[2];
  const float* wq     = (const float*)d_in[3];
  const float* bq     = (const float*)d_in[4];
  const float* wk     = (const float*)d_in[5];
  const float* bk     = (const float*)d_in[6];
  const float* wv     = (const float*)d_in[7];
  const float* bv     = (const float*)d_in[8];
  const float* swq    = (const float*)d_in[9];
  const float* sbq    = (const float*)d_in[10];
  const float* swk    = (const float*)d_in[11];
  const float* sbk    = (const float*)d_in[12];
  const float* swv    = (const float*)d_in[13];
  const float* sbv    = (const float*)d_in[14];
  const float* proj_w = (const float*)d_in[15];
  const float* bn_g   = (const float*)d_in[16];
  const float* bn_b   = (const float*)d_in[17];
  const float* bn_m   = (const float*)d_in[18];
  const float* bn_v   = (const float*)d_in[19];
  const float* ln2_g  = (const float*)d_in[20];
  const float* ln2_b  = (const float*)d_in[21];
  const float* w1     = (const float*)d_in[22];
  const float* b1     = (const float*)d_in[23];
  const float* w2     = (const float*)d_in[24];
  const float* b2     = (const float*)d_in[25];

  char* W = (char*)d_ws;
  const size_t SZB = 20480000;  // bytes per 16*512*625 f32 slot
  char* S0 = W;
  char* S1 = W + SZB;
  char* S2 = W + 2 * SZB;
  char* S3 = W + 3 * SZB;
  char* S4 = W + 4 * SZB;

  float*  xln   = (float*)S0;
  float*  qb    = (float*)S1;
  float*  kb    = (float*)S2;
  float*  vb    = (float*)S3;
  __bf16* qT    = (__bf16*)S0;
  __bf16* kTp   = qT + (size_t)BATCH * HEADS * NPIX * 64;
  __bf16* v16   = (__bf16*)d_out;
  float*  ab    = (float*)S4;
  __bf16* sq16  = (__bf16*)S1;
  __bf16* sk16  = (__bf16*)S2;
  float*  sv    = (float*)S3;
  __bf16* svT   = (__bf16*)S4;
  __bf16* Amat  = (__bf16*)S0;
  __bf16* pw16  = (__bf16*)(S0 + 10485760);
  __bf16* w116  = (__bf16*)(S0 + 10485760 + 524288);
  __bf16* w216  = (__bf16*)(S0 + 10485760 + 524288 + 2097152);
  float*  bnsc  = (float*)(S0 + 10485760 + 524288 + 2097152 + 2097152);
  float*  bnsh  = bnsc + CH;
  __bf16* xoutT = (__bf16*)S1;
  float*  x_nc  = (float*)S4;
  float*  y1_nc = (float*)S3;
  __bf16* y1ln  = (__bf16*)S0;
  __bf16* h1T   = (__bf16*)S1;   // spans S1+S2
  float*  tmp_nc = (float*)S4;

  const size_t SZ = (size_t)BATCH * CH * NPIX;

  // 1. LN1: x -> xln [c][n]
  ln_kernel2<<<dim3(10, BATCH), 256, 0, stream>>>(x, ln1_g, ln1_b, xln);
  // 2. q,k,v depthwise convs (25x25), f32
  dwconv3_kernel<<<(int)((SZ + 255) / 256), 256, 0, stream>>>(
      xln, wq, bq, wk, bk, wv, bv, qb, kb, vb, 25, 25);
  // 3. bf16 conversions for head attention
  qk_to_bf16T<<<dim3(10, BATCH * HEADS), 256, 0, stream>>>(qb, kb, qT, kTp);
  v_to_bf16<<<dim3(BATCH * CH), 256, 0, stream>>>(vb, v16);
  // 4. MFMA head attention v5 (64 q-rows/block, register P) -> ab [c][n] f32
  head_attn_mfma5<<<dim3(10, HEADS, BATCH), 256, 0, stream>>>(qT, kTp, v16, ab);
  // 5. spe convs (5x125): sq16,sk16 bf16 [c][640]; sv f32 [c][625]
  dwconv_spe_kernel<<<(int)(((size_t)BATCH * CH * 640 + 255) / 256), 256, 0, stream>>>(
      ab, swq, sbq, swk, sbk, swv, sbv, sq16, sk16, sv);
  // 6. sv -> svT bf16 [b][625][512]
  transpose_bat<__bf16><<<dim3(10, 8, BATCH), 256, 0, stream>>>(sv, svT, CH, NPIX);
  // 7. weight casts + BN fold
  cast_bf16_kernel<<<1024, 256, 0, stream>>>(proj_w, pw16, CH * CH);
  cast_bf16_kernel<<<4096, 256, 0, stream>>>(w1, w116, HIDD * CH);
  cast_bf16_kernel<<<4096, 256, 0, stream>>>(w2, w216, CH * HIDD);
  bn_prep<<<2, 256, 0, stream>>>(bn_g, bn_b, bn_m, bn_v, bnsc, bnsh);
  // 8. channel attention v2 -> Amat bf16 [b][512][512]
  chan_attn_mfma2<<<dim3(32, BATCH), 256, 0, stream>>>(sq16, sk16, Amat);
  // 9. G1: xoutT[b] = svT (625x512) . Amat^T -> bf16 [b][625][512]
  gemm_nt<0><<<dim3(8, 5, BATCH), 256, 0, stream>>>(
      svT, (long long)NPIX * CH, Amat, (long long)CH * CH,
      xoutT, (long long)NPIX * CH, NPIX, CH, CH,
      nullptr, nullptr, nullptr, 0);
  // 10. x -> x_nc f32 [b][625][512]
  transpose_bat<float><<<dim3(10, 8, BATCH), 256, 0, stream>>>(x, x_nc, CH, NPIX);
  // 11. G2: y1_nc = BN(xoutT . pw16^T) + x_nc   (f32, [10000][512])
  gemm_nt<1><<<dim3(8, 79, 1), 256, 0, stream>>>(
      xoutT, 0LL, pw16, 0LL, y1_nc, 0LL, BATCH * NPIX, CH, CH,
      bnsc, bnsh, x_nc, 0LL);
  // 12. LN2 (row-wise) -> y1ln bf16
  ln2_row_kernel<<<BATCH * NPIX / 4, 256, 0, stream>>>(y1_nc, ln2_g, ln2_b, y1ln);
  // 13. G3: h1T = gelu(y1ln . w116^T + b1)  bf16 [10000][2048]
  gemm_nt<2><<<dim3(32, 79, 1), 256, 0, stream>>>(
      y1ln, 0LL, w116, 0LL, h1T, 0LL, BATCH * NPIX, HIDD, CH,
      b1, nullptr, nullptr, 0LL);
  // 14. G4: tmp_nc = h1T . w216^T + b2 + y1_nc  (f32 [10000][512])
  gemm_nt<3><<<dim3(8, 79, 1), 256, 0, stream>>>(
      h1T, 0LL, w216, 0LL, tmp_nc, 0LL, BATCH * NPIX, CH, HIDD,
      b2, nullptr, y1_nc, 0LL);
  // 15. tmp_nc [b][625][512] -> d_out [b][512][625]
  transpose_bat<float><<<dim3(8, 10, BATCH), 256, 0, stream>>>(
      tmp_nc, (float*)d_out, NPIX, CH);
}